// Round 1
// baseline (166.560 us; speedup 1.0000x reference)
//
#include <hip/hip_runtime.h>

// Problem dims (fixed by reference)
#define T_TOTAL (32 * 4096)   // B*S = 131072 tokens
#define FDIM 256
#define NG 2                  // groups
#define NN 128                // entries per group
#define DDIM 128              // group dim
#define EDIM 256              // embed dim

// ---------------------------------------------------------------------------
// Kernel A: CO[g][n][e] = sum_d codebooks[g][n][d] * W_out[g*128+d][e]
// One block per (g,n); 256 threads = one e each.
// ---------------------------------------------------------------------------
__global__ __launch_bounds__(256) void co_kernel(
    const float* __restrict__ codebooks,  // [2][128][128]
    const float* __restrict__ W_out,      // [256][256]
    float* __restrict__ CO)               // [2][128][256]
{
    const int gn = blockIdx.x;            // 0..255 ; g = gn>>7
    const int g  = gn >> 7;
    __shared__ float cb[DDIM];
    const int tid = threadIdx.x;
    if (tid < DDIM) cb[tid] = codebooks[gn * DDIM + tid];
    __syncthreads();
    float acc = 0.f;
    const float* wcol = W_out + (g * DDIM) * EDIM + tid;
#pragma unroll 4
    for (int d = 0; d < DDIM; ++d) acc += cb[d] * wcol[d * EDIM];
    CO[gn * EDIM + tid] = acc;
}

// ---------------------------------------------------------------------------
// Kernel B: per (token-tile, group): logits = F_g @ Wl_g ; noisy = logits +
// b_logits + gumbel ; argmax over n. Writes index (as float) to idx_f.
// Block: 256 threads, 64 tokens, all 128 n, K=128 in two 64-phases.
// Thread (tq,nq): tokens tq*4..tq*4+3, n in {nq*4..nq*4+3} u {64+nq*4..67+nq*4}
// ---------------------------------------------------------------------------
__global__ __launch_bounds__(256) void logits_argmax_kernel(
    const float* __restrict__ features,   // [T][256]
    const float* __restrict__ gumbel,     // [T][2][128]
    const float* __restrict__ Wl,         // [2][128][128]  (g,d,n)
    const float* __restrict__ bl,         // [2][128]
    float* __restrict__ idx_f)            // [T][2] (float-encoded indices)
{
    __shared__ float Ft[64][64];    // [k][t]  16 KB (transposed)
    __shared__ float Wt[64][128];   // [k][n]  32 KB

    const int g   = blockIdx.y;
    const int t0  = blockIdx.x * 64;
    const int tid = threadIdx.x;
    const int tq  = tid >> 4;     // 0..15
    const int nq  = tid & 15;     // 0..15

    float acc[4][8];
#pragma unroll
    for (int i = 0; i < 4; ++i)
#pragma unroll
        for (int j = 0; j < 8; ++j) acc[i][j] = 0.f;

    for (int p = 0; p < 2; ++p) {
        // ---- stage F tile, transposed. lane l = token, w selects k-chunk.
        {
            const int l = tid & 63;
            const int w = tid >> 6;   // 0..3
            const float* src = features + (size_t)(t0 + l) * FDIM + g * DDIM + p * 64;
#pragma unroll
            for (int i = 0; i < 4; ++i) {
                const int kq = i * 4 + w;   // 0..15
                const float4 v = *reinterpret_cast<const float4*>(src + kq * 4);
                Ft[kq * 4 + 0][l] = v.x;
                Ft[kq * 4 + 1][l] = v.y;
                Ft[kq * 4 + 2][l] = v.z;
                Ft[kq * 4 + 3][l] = v.w;
            }
        }
        // ---- stage W tile (row-linear, coalesced)
        {
            const float* wbase = Wl + ((size_t)g * DDIM + p * 64) * NN;
#pragma unroll
            for (int i = 0; i < 8; ++i) {
                const int s    = tid + i * 256;   // 0..2047
                const int kloc = s >> 5;          // 0..63
                const int nc   = s & 31;          // float4 column
                const float4 v = *reinterpret_cast<const float4*>(wbase + kloc * NN + nc * 4);
                *reinterpret_cast<float4*>(&Wt[kloc][nc * 4]) = v;
            }
        }
        __syncthreads();

#pragma unroll 2
        for (int k = 0; k < 64; ++k) {
            const float4 f  = *reinterpret_cast<const float4*>(&Ft[k][tq * 4]);
            const float4 w0 = *reinterpret_cast<const float4*>(&Wt[k][nq * 4]);
            const float4 w1 = *reinterpret_cast<const float4*>(&Wt[k][64 + nq * 4]);
#pragma unroll
            for (int i = 0; i < 4; ++i) {
                const float fi = (i == 0) ? f.x : (i == 1) ? f.y : (i == 2) ? f.z : f.w;
                acc[i][0] += fi * w0.x;
                acc[i][1] += fi * w0.y;
                acc[i][2] += fi * w0.z;
                acc[i][3] += fi * w0.w;
                acc[i][4] += fi * w1.x;
                acc[i][5] += fi * w1.y;
                acc[i][6] += fi * w1.z;
                acc[i][7] += fi * w1.w;
            }
        }
        __syncthreads();
    }

    // ---- epilogue: + b_logits + gumbel, argmax over n (16-lane groups)
    const float4 b0 = *reinterpret_cast<const float4*>(bl + g * NN + nq * 4);
    const float4 b1 = *reinterpret_cast<const float4*>(bl + g * NN + 64 + nq * 4);

#pragma unroll
    for (int i = 0; i < 4; ++i) {
        const int t = t0 + tq * 4 + i;
        const float* grow = gumbel + ((size_t)t * NG + g) * NN;
        const float4 g0 = *reinterpret_cast<const float4*>(grow + nq * 4);
        const float4 g1 = *reinterpret_cast<const float4*>(grow + 64 + nq * 4);

        float v[8];
        v[0] = acc[i][0] + b0.x + g0.x;
        v[1] = acc[i][1] + b0.y + g0.y;
        v[2] = acc[i][2] + b0.z + g0.z;
        v[3] = acc[i][3] + b0.w + g0.w;
        v[4] = acc[i][4] + b1.x + g1.x;
        v[5] = acc[i][5] + b1.y + g1.y;
        v[6] = acc[i][6] + b1.z + g1.z;
        v[7] = acc[i][7] + b1.w + g1.w;

        float m  = v[0];
        int   bi = nq * 4;
#pragma unroll
        for (int j = 1; j < 4; ++j)
            if (v[j] > m) { m = v[j]; bi = nq * 4 + j; }
#pragma unroll
        for (int j = 4; j < 8; ++j)
            if (v[j] > m) { m = v[j]; bi = 64 + nq * 4 + (j - 4); }

        // reduce across the 16 lanes sharing this token (lanes aligned mod 16)
#pragma unroll
        for (int off = 1; off < 16; off <<= 1) {
            const float om = __shfl_xor(m, off);
            const int   ob = __shfl_xor(bi, off);
            if (om > m || (om == m && ob < bi)) { m = om; bi = ob; }
        }
        if (nq == 0) idx_f[t * NG + g] = (float)bi;
    }
}

// ---------------------------------------------------------------------------
// Kernel C: out[t][e] = CO[0][i0][e] + CO[1][i1][e] + b_out[e]
// 256 threads = 64 float4-lanes x 4 token slots; 16 tokens per block.
// ---------------------------------------------------------------------------
__global__ __launch_bounds__(256) void out_kernel(
    const float* __restrict__ CO,      // [2][128][256]
    const float* __restrict__ b_out,   // [256]
    const float* __restrict__ idx_f,   // [T][2] float-encoded
    float* __restrict__ out)           // [T][256]
{
    const int tid = threadIdx.x;
    const int e4  = tid & 63;    // float4 index in e
    const int ts  = tid >> 6;    // 0..3
    const int tbase = blockIdx.x * 16;
    const float4 b = *reinterpret_cast<const float4*>(b_out + e4 * 4);

#pragma unroll
    for (int it = 0; it < 4; ++it) {
        const int t  = tbase + it * 4 + ts;
        const int i0 = (int)idx_f[t * NG + 0];
        const int i1 = (int)idx_f[t * NG + 1];
        const float4 c0 = *reinterpret_cast<const float4*>(CO + (size_t)i0 * EDIM + e4 * 4);
        const float4 c1 = *reinterpret_cast<const float4*>(CO + (size_t)(NN + i1) * EDIM + e4 * 4);
        float4 o;
        o.x = c0.x + c1.x + b.x;
        o.y = c0.y + c1.y + b.y;
        o.z = c0.z + c1.z + b.z;
        o.w = c0.w + c1.w + b.w;
        *reinterpret_cast<float4*>(out + (size_t)t * EDIM + e4 * 4) = o;
    }
}

// ---------------------------------------------------------------------------
extern "C" void kernel_launch(void* const* d_in, const int* in_sizes, int n_in,
                              void* d_out, int out_size, void* d_ws, size_t ws_size,
                              hipStream_t stream) {
    const float* features  = (const float*)d_in[0];  // [32,4096,256]
    const float* gumbel    = (const float*)d_in[1];  // [32,4096,2,128]
    const float* Wl        = (const float*)d_in[2];  // [2,128,128]
    const float* bl        = (const float*)d_in[3];  // [2,128]
    const float* codebooks = (const float*)d_in[4];  // [2,128,128]
    const float* W_out     = (const float*)d_in[5];  // [256,256]
    const float* b_out     = (const float*)d_in[6];  // [256]

    float* out   = (float*)d_out;                          // [T,256]
    float* idx_f = out + (size_t)T_TOTAL * EDIM;           // [T,2] float-encoded indices
    float* CO    = (float*)d_ws;                           // [2,128,256] = 256 KB

    co_kernel<<<NG * NN, 256, 0, stream>>>(codebooks, W_out, CO);
    logits_argmax_kernel<<<dim3(T_TOTAL / 64, NG), 256, 0, stream>>>(
        features, gumbel, Wl, bl, idx_f);
    out_kernel<<<T_TOTAL / 16, 256, 0, stream>>>(CO, b_out, idx_f, out);
}